// Round 17
// baseline (247.398 us; speedup 1.0000x reference)
//
#include <hip/hip_runtime.h>
#include <math.h>

#define B_  128
#define N_  21
#define D_  300
#define NPAIRS 231                  // upper-tri incl diag
#define NPAIR_TOT (B_ * NPAIRS)     // 29568
#define GRID_E (NPAIR_TOT / 32)     // 924 edge blocks (32 pairs each)
#define NROWS (B_ * N_)             // 2688
#define DP  320

typedef __attribute__((ext_vector_type(8))) short short8v;
typedef __attribute__((ext_vector_type(4))) short short4v;
typedef __attribute__((ext_vector_type(4))) float f32x4;

__device__ __forceinline__ float lrelu(float v) { return v > 0.f ? v : 0.01f * v; }

__device__ __forceinline__ unsigned short f2bf(float f) {
    unsigned u = __builtin_bit_cast(unsigned, f);
    u += 0x7FFFu + ((u >> 16) & 1u);
    return (unsigned short)(u >> 16);
}
__device__ __forceinline__ float bf2f(unsigned short h) {
    unsigned u = ((unsigned)h) << 16;
    return __builtin_bit_cast(float, u);
}

// ---------------------------------------------------------------------------
// One prep kernel: edge weights (2 layers) + node weights -> bf16 hi/lo.
__global__ __launch_bounds__(256) void prep_all(
    const float* __restrict__ e00, const float* __restrict__ e01, const float* __restrict__ e02,
    const float* __restrict__ e10, const float* __restrict__ e11, const float* __restrict__ e12,
    const float* __restrict__ n0n, const float* __restrict__ n0r,
    const float* __restrict__ n1n, const float* __restrict__ n1r,
    unsigned short* __restrict__ ewb, unsigned short* __restrict__ nwb, int do_node)
{
    int idx = blockIdx.x * 256 + threadIdx.x;   // grid 2624 -> 671744 exact
    float v; unsigned short *ph, *pl; int off;
    if (idx < 262144) {
        int l = idx >> 17;
        int t = idx & 131071;
        unsigned short* blk = ewb + (size_t)l * 262144;
        const float* w0 = l ? e10 : e00;
        const float* w1 = l ? e11 : e01;
        const float* w2 = l ? e12 : e02;
        if (t < 81920) {
            int n = t / 320, k = t - n * 320;
            v = (k < 300) ? w0[n * 300 + k] : 0.f;
            ph = blk; pl = blk + 81920; off = t;
        } else if (t < 114688) {
            int r = t - 81920; v = w1[r];
            ph = blk + 163840; pl = blk + 196608; off = r;
        } else {
            int r = t - 114688; v = w2[r];
            ph = blk + 229376; pl = blk + 245760; off = r;
        }
    } else {
        if (!do_node) return;
        int t = idx - 262144;                    // 0 .. 409599
        int l = t / 204800;
        int r = t - l * 204800;
        int mat = r / 102400;
        int q = r - mat * 102400;
        int n = q / 320, k = q - n * 320;
        const float* src = l ? (mat ? n1r : n1n) : (mat ? n0r : n0n);
        v = (n < 300 && k < 300) ? src[n * 300 + k] : 0.f;
        unsigned short* blk = nwb + (size_t)l * 409600;
        ph = blk + mat * 204800; pl = ph + 102400; off = q;
    }
    unsigned short hb = f2bf(v);
    ph[off] = hb; pl[off] = f2bf(v - bf2f(hb));
}

// ---------------------------------------------------------------------------
// Edge MLP, wave = channel-quarter x ALL 32 pairs:
//   - weights: global -> registers per wave (each element read by ONE wave)
//   - activations/h0/h1: shared via LDS (round-5-verified packed layouts)
//   - G2/G3 are barrier-free (h0/h1 read-only)
// LDS 48KB -> 3 blocks/CU.
// lds layout (ushort offsets): xijh[sel]@sel*1024, xijl[sel]@2048+sel*1024,
//   h0h@4096(8192), h0l@12288(8192), h1h@0(4096, reuses dead xij),
//   h1l@20480(4096), spart(float[128]) @ byte 8192 (dead h0 region).
__global__ __launch_bounds__(256, 3) void edge_mfma(
    const float* __restrict__ x,
    const unsigned short* __restrict__ w0h, const unsigned short* __restrict__ w0l,
    const unsigned short* __restrict__ w1h, const unsigned short* __restrict__ w1l,
    const unsigned short* __restrict__ w2h, const unsigned short* __restrict__ w2l,
    const float* __restrict__ wo, const float* __restrict__ bo,
    float* __restrict__ adjraw)
{
    __shared__ __align__(16) unsigned short lds[24576];   // 48 KB

    const int tid  = threadIdx.x;
    const int lane = tid & 63;
    const int w    = tid >> 6;
    const int l15  = lane & 15;
    const int l4   = lane >> 4;
    const int P0   = blockIdx.x * 32;

    // staging coords: pair row sm (0..31), k-quad sq (0..7)
    const int sm = tid >> 3;
    const int sq = tid & 7;
    const float *xi, *xj;
    {
        int p = P0 + sm;
        int bb = p / NPAIRS;
        int u = p - bb * NPAIRS;
        int ii = 0;
        while (u >= N_ - ii) { u -= N_ - ii; ++ii; }
        int jj = ii + u;
        xi = x + ((size_t)bb * N_ + ii) * D_;
        xj = x + ((size_t)bb * N_ + jj) * D_;
    }
    const int xw_off = sm * 32 + (((sq >> 1) ^ ((sm >> 1) & 3)) << 3) + ((sq & 1) << 2);

    auto stage = [&](int c, int sel) {
        const int d0 = c * 32 + sq * 4;
        short4v hv = (short4v){0, 0, 0, 0}, lv = (short4v){0, 0, 0, 0};
        if (d0 < D_) {                       // D_%4==0 -> full float4 safe
            float4 xa = *(const float4*)(xi + d0);
            float4 xbv = *(const float4*)(xj + d0);
            #pragma unroll
            for (int e = 0; e < 4; ++e) {
                float v = expf(-fabsf((&xa.x)[e] - (&xbv.x)[e]));
                unsigned short hb = f2bf(v);
                hv[e] = (short)hb;
                lv[e] = (short)f2bf(v - bf2f(hb));
            }
        }
        *(short4v*)(lds + sel * 1024 + xw_off) = hv;
        *(short4v*)(lds + 2048 + sel * 1024 + xw_off) = lv;
    };

    // ---------------- G1: h0 = w0 @ xij^T, K=320 (10 chunks) ----------------
    // wave w: channel tiles w*4..w*4+3 (64 chans), pair groups pg=0,1
    f32x4 acc[8];                            // acc[t*2+pg]
    #pragma unroll
    for (int t = 0; t < 8; ++t) acc[t] = (f32x4){0.f, 0.f, 0.f, 0.f};

    stage(0, 0);
    __syncthreads();

    #pragma unroll 1
    for (int c = 0; c < 10; ++c) {
        const int sel = c & 1;
        const int kg = c * 32 + l4 * 8;
        short8v wh[4], wl[4];
        #pragma unroll
        for (int t = 0; t < 4; ++t) {
            const size_t n = (size_t)((w * 4 + t) * 16 + l15);
            wh[t] = *(const short8v*)(w0h + n * 320 + kg);
            wl[t] = *(const short8v*)(w0l + n * 320 + kg);
        }
        if (c < 9) stage(c + 1, sel ^ 1);
        short8v bh[2], bl[2];
        #pragma unroll
        for (int pg = 0; pg < 2; ++pg) {
            const int row = pg * 16 + l15;
            const int off = row * 32 + ((l4 ^ ((row >> 1) & 3)) << 3);
            bh[pg] = *(const short8v*)(lds + sel * 1024 + off);
            bl[pg] = *(const short8v*)(lds + 2048 + sel * 1024 + off);
        }
        #pragma unroll
        for (int t = 0; t < 4; ++t) {
            #pragma unroll
            for (int pg = 0; pg < 2; ++pg) {
                acc[t*2+pg] = __builtin_amdgcn_mfma_f32_16x16x32_bf16(wh[t], bh[pg], acc[t*2+pg], 0, 0, 0);
                acc[t*2+pg] = __builtin_amdgcn_mfma_f32_16x16x32_bf16(wh[t], bl[pg], acc[t*2+pg], 0, 0, 0);
                acc[t*2+pg] = __builtin_amdgcn_mfma_f32_16x16x32_bf16(wl[t], bh[pg], acc[t*2+pg], 0, 0, 0);
            }
        }
        __syncthreads();
    }

    // store h0[pair][chan] hi/lo, packed b64 (round-5 verified layout)
    #pragma unroll
    for (int t = 0; t < 4; ++t) {
        #pragma unroll
        for (int pg = 0; pg < 2; ++pg) {
            short4v hv, lv;
            #pragma unroll
            for (int r = 0; r < 4; ++r) {
                float f = lrelu(acc[t*2+pg][r]);
                unsigned short hb = f2bf(f);
                hv[r] = (short)hb;
                lv[r] = (short)f2bf(f - bf2f(hb));
            }
            const int row = pg * 16 + l15;
            const int bswz = row & 7;
            const int chanb = w * 64 + t * 16 + l4 * 4;
            const int uo = (((chanb >> 3) ^ bswz) << 3) + ((l4 & 1) << 2);
            *(short4v*)(lds + 4096 + row * 256 + uo) = hv;
            *(short4v*)(lds + 12288 + row * 256 + uo) = lv;
        }
    }
    __syncthreads();

    // ---------------- G2: h1 = w1 @ h0^T, K=256 (8 chunks, NO barriers) ----
    f32x4 acc2[4];                           // acc2[q*2+pg]
    #pragma unroll
    for (int t = 0; t < 4; ++t) acc2[t] = (f32x4){0.f, 0.f, 0.f, 0.f};

    #pragma unroll
    for (int ks = 0; ks < 8; ++ks) {
        const int kg = ks * 32 + l4 * 8;
        short8v wh[2], wl[2];
        #pragma unroll
        for (int q = 0; q < 2; ++q) {
            const size_t n = (size_t)((w * 2 + q) * 16 + l15);
            wh[q] = *(const short8v*)(w1h + n * 256 + kg);
            wl[q] = *(const short8v*)(w1l + n * 256 + kg);
        }
        const int u = ks * 4 + l4;
        short8v bh[2], bl[2];
        #pragma unroll
        for (int pg = 0; pg < 2; ++pg) {
            const int row = pg * 16 + l15;
            const int off = row * 256 + ((u ^ (row & 7)) << 3);
            bh[pg] = *(const short8v*)(lds + 4096 + off);
            bl[pg] = *(const short8v*)(lds + 12288 + off);
        }
        #pragma unroll
        for (int q = 0; q < 2; ++q) {
            #pragma unroll
            for (int pg = 0; pg < 2; ++pg) {
                acc2[q*2+pg] = __builtin_amdgcn_mfma_f32_16x16x32_bf16(wh[q], bh[pg], acc2[q*2+pg], 0, 0, 0);
                acc2[q*2+pg] = __builtin_amdgcn_mfma_f32_16x16x32_bf16(wh[q], bl[pg], acc2[q*2+pg], 0, 0, 0);
                acc2[q*2+pg] = __builtin_amdgcn_mfma_f32_16x16x32_bf16(wl[q], bh[pg], acc2[q*2+pg], 0, 0, 0);
            }
        }
    }

    // store h1 (h1h reuses dead xij region @0; h1l @20480)
    #pragma unroll
    for (int q = 0; q < 2; ++q) {
        #pragma unroll
        for (int pg = 0; pg < 2; ++pg) {
            short4v hv, lv;
            #pragma unroll
            for (int r = 0; r < 4; ++r) {
                float f = lrelu(acc2[q*2+pg][r]);
                unsigned short hb = f2bf(f);
                hv[r] = (short)hb;
                lv[r] = (short)f2bf(f - bf2f(hb));
            }
            const int row = pg * 16 + l15;
            const int bswz = row & 7;
            const int chanb = w * 32 + q * 16 + l4 * 4;
            const int uo = (((chanb >> 3) ^ bswz) << 3) + ((l4 & 1) << 2);
            *(short4v*)(lds + row * 128 + uo) = hv;
            *(short4v*)(lds + 20480 + row * 128 + uo) = lv;
        }
    }
    __syncthreads();

    // ---------------- G3: h2 = w2 @ h1^T, K=128 (4 chunks, NO barriers) ----
    f32x4 acc3[4];
    #pragma unroll
    for (int t = 0; t < 4; ++t) acc3[t] = (f32x4){0.f, 0.f, 0.f, 0.f};

    #pragma unroll
    for (int ks = 0; ks < 4; ++ks) {
        const int kg = ks * 32 + l4 * 8;
        short8v wh[2], wl[2];
        #pragma unroll
        for (int q = 0; q < 2; ++q) {
            const size_t n = (size_t)((w * 2 + q) * 16 + l15);
            wh[q] = *(const short8v*)(w2h + n * 128 + kg);
            wl[q] = *(const short8v*)(w2l + n * 128 + kg);
        }
        const int u = ks * 4 + l4;
        short8v bh[2], bl[2];
        #pragma unroll
        for (int pg = 0; pg < 2; ++pg) {
            const int row = pg * 16 + l15;
            const int off = row * 128 + ((u ^ (row & 7)) << 3);
            bh[pg] = *(const short8v*)(lds + off);
            bl[pg] = *(const short8v*)(lds + 20480 + off);
        }
        #pragma unroll
        for (int q = 0; q < 2; ++q) {
            #pragma unroll
            for (int pg = 0; pg < 2; ++pg) {
                acc3[q*2+pg] = __builtin_amdgcn_mfma_f32_16x16x32_bf16(wh[q], bh[pg], acc3[q*2+pg], 0, 0, 0);
                acc3[q*2+pg] = __builtin_amdgcn_mfma_f32_16x16x32_bf16(wh[q], bl[pg], acc3[q*2+pg], 0, 0, 0);
                acc3[q*2+pg] = __builtin_amdgcn_mfma_f32_16x16x32_bf16(wl[q], bh[pg], acc3[q*2+pg], 0, 0, 0);
            }
        }
    }

    // ---------------- sim: per-wave 32-chan partials -> LDS -> final -------
    float ps0 = 0.f, ps1 = 0.f;
    #pragma unroll
    for (int q = 0; q < 2; ++q) {
        float4 wov = *(const float4*)(wo + w * 32 + q * 16 + l4 * 4);
        #pragma unroll
        for (int r = 0; r < 4; ++r) {
            ps0 += lrelu(acc3[q*2+0][r]) * (&wov.x)[r];
            ps1 += lrelu(acc3[q*2+1][r]) * (&wov.x)[r];
        }
    }
    ps0 += __shfl_xor(ps0, 16); ps0 += __shfl_xor(ps0, 32);
    ps1 += __shfl_xor(ps1, 16); ps1 += __shfl_xor(ps1, 32);
    float* spart = (float*)(lds + 4096);     // dead h0h region
    if (l4 == 0) {
        spart[w * 32 + l15]      = ps0;
        spart[w * 32 + 16 + l15] = ps1;
    }
    __syncthreads();

    if (tid < 32) {
        float sim = spart[tid] + spart[32 + tid] + spart[64 + tid] + spart[96 + tid] + bo[0];
        float a = 1.f / (1.f + expf(-sim));
        int p = P0 + tid;
        int bb = p / NPAIRS;
        int u = p - bb * NPAIRS;
        int ii = 0;
        while (u >= N_ - ii) { u -= N_ - ii; ++ii; }
        int jj = ii + u;
        if (ii == jj) a = 0.f;
        adjraw[(size_t)bb * 441 + ii * 21 + jj] = a;
        adjraw[(size_t)bb * 441 + jj * 21 + ii] = a;
    }
}

// ---------------------------------------------------------------------------
// Node GEMM via MFMA (round-11/14 proven): 16-row M-blocks, grid (168, 2).
__global__ __launch_bounds__(256, 4) void node_gemm(
    const float* __restrict__ xin,
    const unsigned short* __restrict__ wnh, const unsigned short* __restrict__ wnl,
    const unsigned short* __restrict__ wrh, const unsigned short* __restrict__ wrl,
    float* __restrict__ nbuf)
{
    __shared__ __align__(16) unsigned short sxh[2][512], sxl[2][512];

    const int tid  = threadIdx.x;
    const int lane = tid & 63;
    const int w    = tid >> 6;
    const int l15  = lane & 15;
    const int l4   = lane >> 4;
    const int M0   = blockIdx.x * 16;
    const int mat  = blockIdx.y;

    const unsigned short* ah_base = mat ? wrh : wnh;
    const unsigned short* al_base = mat ? wrl : wnl;
    float* ob = nbuf + (size_t)mat * NROWS * DP;

    const int sm = tid >> 4;
    const int sk = (tid & 15) * 2;
    const float* xrow = xin + (size_t)(M0 + sm) * D_;
    const int sa = sm * 32 + (((sk >> 3) ^ ((sm >> 1) & 3)) << 3) + (sk & 7);
    const int xr_off = l15 * 32 + ((l4 ^ ((l15 >> 1) & 3)) << 3);

    f32x4 acc[5];
    #pragma unroll
    for (int t = 0; t < 5; ++t) acc[t] = (f32x4){0.f, 0.f, 0.f, 0.f};

    {
        float2 v = *(const float2*)(xrow + sk);
        unsigned short h0 = f2bf(v.x), h1 = f2bf(v.y);
        unsigned uh = (unsigned)h0 | ((unsigned)h1 << 16);
        unsigned ul = (unsigned)f2bf(v.x - bf2f(h0)) |
                      ((unsigned)f2bf(v.y - bf2f(h1)) << 16);
        *(unsigned*)(&sxh[0][sa]) = uh;
        *(unsigned*)(&sxl[0][sa]) = ul;
    }
    __syncthreads();

    #pragma unroll 1
    for (int c = 0; c < 10; ++c) {
        const int sel = c & 1;
        short8v wh[5], wl[5];
        const int kg = c * 32 + l4 * 8;
        #pragma unroll
        for (int t = 0; t < 5; ++t) {
            const size_t n = (size_t)((w * 5 + t) * 16 + l15);
            wh[t] = *(const short8v*)(ah_base + n * DP + kg);
            wl[t] = *(const short8v*)(al_base + n * DP + kg);
        }
        float2 xv; bool have = false;
        if (c < 9) {
            const int k0 = (c + 1) * 32 + sk;
            if (k0 < D_) { xv = *(const float2*)(xrow + k0); have = true; }
        }
        short8v bh = *(const short8v*)(sxh[sel] + xr_off);
        short8v bl = *(const short8v*)(sxl[sel] + xr_off);
        #pragma unroll
        for (int t = 0; t < 5; ++t) {
            acc[t] = __builtin_amdgcn_mfma_f32_16x16x32_bf16(wh[t], bh, acc[t], 0, 0, 0);
            acc[t] = __builtin_amdgcn_mfma_f32_16x16x32_bf16(wh[t], bl, acc[t], 0, 0, 0);
            acc[t] = __builtin_amdgcn_mfma_f32_16x16x32_bf16(wl[t], bh, acc[t], 0, 0, 0);
        }
        if (c < 9) {
            unsigned uh = 0, ul = 0;
            if (have) {
                unsigned short h0 = f2bf(xv.x), h1 = f2bf(xv.y);
                uh = (unsigned)h0 | ((unsigned)h1 << 16);
                ul = (unsigned)f2bf(xv.x - bf2f(h0)) |
                     ((unsigned)f2bf(xv.y - bf2f(h1)) << 16);
            }
            *(unsigned*)(&sxh[sel ^ 1][sa]) = uh;
            *(unsigned*)(&sxl[sel ^ 1][sa]) = ul;
        }
        __syncthreads();
    }

    #pragma unroll
    for (int t = 0; t < 5; ++t) {
        const int n0 = (w * 5 + t) * 16 + l4 * 4;
        float4 v;
        v.x = acc[t][0]; v.y = acc[t][1]; v.z = acc[t][2]; v.w = acc[t][3];
        *(float4*)(ob + (size_t)(M0 + l15) * DP + n0) = v;
    }
}

// ---------------------------------------------------------------------------
// Per-batch fused top-k + combine (round-12 proven): P panel read once per b.
__global__ __launch_bounds__(320) void node_combine(
    const float* __restrict__ adjraw, const float* __restrict__ nbuf,
    const float* __restrict__ bn, const float* __restrict__ br,
    const float* __restrict__ eemb, float* __restrict__ out)
{
    const int b = blockIdx.x;
    const int tid = threadIdx.x;
    __shared__ float sadj[N_][24];
    __shared__ float sA[N_][24];
    __shared__ float srs[N_];

    for (int it = tid; it < N_ * N_; it += 320) {
        int t = it / N_, s = it - (it / N_) * N_;
        sadj[t][s] = adjraw[(size_t)b * 441 + it];
    }
    __syncthreads();
    if (tid < N_) {
        unsigned used = 0;
        for (int r = 0; r < 5; ++r) {
            float best = -1.f; int bi = 0;
            for (int j = 0; j < N_; ++j) {
                if (used & (1u << j)) continue;
                if (sadj[tid][j] > best) { best = sadj[tid][j]; bi = j; }
            }
            used |= (1u << bi);
        }
        float rs = 0.f;
        for (int j = 0; j < N_; ++j) {
            float m = ((used >> j) & 1u) ? sadj[tid][j] : 0.f;
            sA[tid][j] = m; rs += m;
        }
        srs[tid] = rs;
    }
    __syncthreads();

    const int o = tid;
    if (o < D_) {
        const float* Pb = nbuf + (size_t)b * N_ * DP;
        const float* Rb = nbuf + (size_t)NROWS * DP + (size_t)b * N_ * DP;
        float pr[N_];
        #pragma unroll
        for (int s = 0; s < N_; ++s) pr[s] = Pb[(size_t)s * DP + o];
        const float bn_o = bn[o], br_o = br[o];
        const float add_o = bn_o + eemb[o];
        #pragma unroll
        for (int t = 0; t < N_; ++t) {
            float m = 0.f;
            #pragma unroll
            for (int s = 0; s < N_; ++s) m += sA[t][s] * pr[s];
            out[((size_t)b * N_ + t) * D_ + o] =
                lrelu((m + srs[t] * add_o) * 0.2f + Rb[(size_t)t * DP + o] + br_o);
        }
    }
}

// ---------------------------------------------------------------------------
// Fallback path (ws too small): top-k + fp32 node kernel
__global__ __launch_bounds__(64) void topk_kernel(
    const float* __restrict__ adjraw, float* __restrict__ A)
{
    const int row = blockIdx.x;
    const int lane = threadIdx.x;
    __shared__ float sadj[32];
    __shared__ unsigned s_used;
    if (lane < N_) sadj[lane] = adjraw[row * N_ + lane];
    __syncthreads();
    if (lane == 0) {
        unsigned used = 0;
        for (int r = 0; r < 5; ++r) {
            float best = -1.f; int bi = 0;
            for (int j = 0; j < N_; ++j) {
                if (used & (1u << j)) continue;
                if (sadj[j] > best) { best = sadj[j]; bi = j; }
            }
            used |= (1u << bi);
        }
        s_used = used;
    }
    __syncthreads();
    if (lane < N_)
        A[row * N_ + lane] = ((s_used >> lane) & 1u) ? sadj[lane] : 0.f;
}

__global__ __launch_bounds__(320) void node_kernel(
    const float* __restrict__ xin, const float* __restrict__ A,
    const float* __restrict__ wn, const float* __restrict__ bn,
    const float* __restrict__ wr, const float* __restrict__ br,
    const float* __restrict__ eemb, float* __restrict__ out)
{
    const int b = blockIdx.x;
    const int tid = threadIdx.x;
    __shared__ float sx[N_][304];
    __shared__ float sA[N_][24];
    __shared__ float srs[N_];

    const float* xb = xin + (size_t)b * N_ * D_;
    for (int it = tid; it < N_ * D_; it += 320) {
        int j = it / D_, d = it - (it / D_) * D_;
        sx[j][d] = xb[it];
    }
    for (int it = tid; it < N_ * N_; it += 320) {
        int t = it / N_, s = it - (it / N_) * N_;
        sA[t][s] = A[((size_t)b * N_ + t) * N_ + s];
    }
    __syncthreads();
    if (tid < N_) {
        float s = 0.f;
        #pragma unroll
        for (int j = 0; j < N_; ++j) s += sA[tid][j];
        srs[tid] = s;
    }
    __syncthreads();

    const int o = tid;
    if (o < D_) {
        float nacc[N_], racc[N_];
        #pragma unroll
        for (int j = 0; j < N_; ++j) { nacc[j] = 0.f; racc[j] = 0.f; }
        const float* wnr = wn + (size_t)o * D_;
        const float* wrr = wr + (size_t)o * D_;
        for (int k4 = 0; k4 < D_; k4 += 4) {
            float4 wn4 = *(const float4*)(wnr + k4);
            float4 wr4 = *(const float4*)(wrr + k4);
            #pragma unroll
            for (int j = 0; j < N_; ++j) {
                float4 xv = *(const float4*)(&sx[j][k4]);
                nacc[j] += wn4.x * xv.x; nacc[j] += wn4.y * xv.y;
                nacc[j] += wn4.z * xv.z; nacc[j] += wn4.w * xv.w;
                racc[j] += wr4.x * xv.x; racc[j] += wr4.y * xv.y;
                racc[j] += wr4.z * xv.z; racc[j] += wr4.w * xv.w;
            }
        }
        const float bn_o = bn[o], br_o = br[o], e0_o = eemb[o];
        const float add_o = bn_o + e0_o;
        #pragma unroll
        for (int t = 0; t < N_; ++t) {
            float m = 0.f;
            #pragma unroll
            for (int s = 0; s < N_; ++s) m += sA[t][s] * nacc[s];
            out[((size_t)b * N_ + t) * D_ + o] =
                lrelu((m + srs[t] * add_o) * 0.2f + racc[t] + br_o);
        }
    }
}

// ---------------------------------------------------------------------------
extern "C" void kernel_launch(void* const* d_in, const int* in_sizes, int n_in,
                              void* d_out, int out_size, void* d_ws, size_t ws_size,
                              hipStream_t stream)
{
    const float* x0 = (const float*)d_in[0];
    auto L = [&](int l, int k) { return (const float*)d_in[1 + l * 10 + k]; };

    // ws layout:
    //   adjraw @0        (225,792)
    //   A      @256KB    (225,792)               (fallback only)
    //   edge w @512KB    (2 x 512KB)             -> ends 1,572,864
    //   node w @1.5MB    (2 x 819,200)           -> ends 3,211,264
    //   nbuf   @3,211,264 (6,881,280)            -> ends 10,092,544
    float* adjraw = (float*)d_ws;
    float* A      = (float*)((char*)d_ws + 262144);
    unsigned short* ewb = (unsigned short*)((char*)d_ws + 524288);
    unsigned short* nwb = (unsigned short*)((char*)d_ws + 1572864);
    float* nbuf   = (float*)((char*)d_ws + 3211264);
    const size_t WS_NEED = 10092544;
    const bool newnode = (ws_size >= WS_NEED);

    prep_all<<<2624, 256, 0, stream>>>(
        L(0,0), L(0,1), L(0,2), L(1,0), L(1,1), L(1,2),
        L(0,5), L(0,7), L(1,5), L(1,7), ewb, nwb, newnode ? 1 : 0);

    for (int l = 0; l < 2; ++l) {
        const float* xin = (l == 0) ? x0 : (const float*)d_out;
        unsigned short* blk = ewb + (size_t)l * 262144;
        edge_mfma<<<GRID_E, 256, 0, stream>>>(xin,
            blk, blk + 81920, blk + 163840, blk + 196608, blk + 229376, blk + 245760,
            L(l, 3), L(l, 4), adjraw);
        if (newnode) {
            unsigned short* nblk = nwb + (size_t)l * 409600;
            node_gemm<<<dim3(NROWS / 16, 2), 256, 0, stream>>>(
                xin, nblk, nblk + 102400, nblk + 204800, nblk + 307200, nbuf);
            node_combine<<<B_, 320, 0, stream>>>(adjraw, nbuf, L(l, 6), L(l, 8),
                                                 L(l, 9), (float*)d_out);
        } else {
            topk_kernel<<<NROWS, 64, 0, stream>>>(adjraw, A);
            node_kernel<<<B_, 320, 0, stream>>>(xin, A, L(l, 5), L(l, 6), L(l, 7),
                                                L(l, 8), L(l, 9), (float*)d_out);
        }
    }
}